// Round 12
// baseline (113.572 us; speedup 1.0000x reference)
//
#include <hip/hip_runtime.h>

// RetinaNet matcher: gt_boxes [B=8, G=64, 4] f32, anchors [A=120000, 4] f32.
// Outputs (concat in d_out, f32): matched_idxs [B,A] (as float), matched_vals [B,A].
//
// Numerics: bit-exact vs np (absmax 0.0 in R5/R6/R8/R9/R10/R11). opaque()
// barriers on every mul result -> no legal FMA-contraction site. div_rn() =
// correctly-rounded divide for mid-range operands (same core as the v_div
// expansion; operands here provably mid-range -> bits identical to v_div).
// argmax tie-break = first g (strict >). IoU >= 0 -> uint atomicMax bit-exact.
//
// R12: (a) asm barriers made NON-volatile: volatile imposed a total order on
// ~300 asm markers per thread, pinning the scheduler; non-volatile keeps the
// contraction block but frees scheduling/CSE. (b) pass1 grid doubled
// (2 anchors/thread, 1880 blocks -> 7.3 waves/SIMD) to fill issue gaps left
// by serial rcp/fma chains (VGPR=24 window -> little intra-thread ILP).
// (c) pass2 reverted to R10 s_load form (R11's VMEM broadcast cost ~5 us).

static constexpr int G = 64;

__device__ __forceinline__ float opaque(float x) {
    asm("" : "+v"(x));  // non-volatile: contraction barrier, scheduler-free
    return x;
}

__device__ __forceinline__ int vindex(int i) {
    asm("" : "+v"(i));  // force VGPR residency; defeats uniformity analysis
    return i;
}

__device__ __forceinline__ float box_area(float x1, float y1, float x2, float y2) {
    return opaque(__fmul_rn(__fsub_rn(x2, x1), __fsub_rn(y2, y1)));
}

__device__ __forceinline__ float inter_area(float gx1, float gy1, float gx2, float gy2,
                                            float ax1, float ay1, float ax2, float ay2) {
    float ltx = fmaxf(gx1, ax1);
    float lty = fmaxf(gy1, ay1);
    float rbx = fminf(gx2, ax2);
    float rby = fminf(gy2, ay2);
    float w = fmaxf(__fsub_rn(rbx, ltx), 0.0f);
    float h = fmaxf(__fsub_rn(rby, lty), 0.0f);
    return opaque(__fmul_rn(w, h));
}

// Correctly-rounded f32 divide for mid-range operands (no denormal/overflow):
// identical arithmetic to the v_div_scale expansion with scale==1.
__device__ __forceinline__ float div_rn(float n, float d) {
    float r = __builtin_amdgcn_rcpf(d);
    float e = fmaf(-d, r, 1.0f);
    r = fmaf(e, r, r);                 // 1 Newton step on rcp
    float q = __fmul_rn(n, r);
    float s = fmaf(-d, q, n);          // exact residual
    q = fmaf(s, r, q);                 // correction 1
    s = fmaf(-d, q, n);
    q = fmaf(s, r, q);                 // correction 2 (div_fmas equivalent)
    return q;
}

// DPP cross-lane max stage on the VALU pipe (no LDS/DS traffic).
#define DPP_MAX_STAGE(x, ctrl)                                                   \
    do {                                                                         \
        int _yi = __builtin_amdgcn_update_dpp(__float_as_int(x),                 \
                                              __float_as_int(x), (ctrl),         \
                                              0xf, 0xf, false);                  \
        (x) = fmaxf((x), __int_as_float(_yi));                                   \
    } while (0)

// Full wave64 max; result valid in lane 63.
__device__ __forceinline__ float wave_max_lane63(float x) {
    DPP_MAX_STAGE(x, 0xB1);   // quad_perm xor1
    DPP_MAX_STAGE(x, 0x4E);   // quad_perm xor2
    DPP_MAX_STAGE(x, 0x141);  // row_half_mirror
    DPP_MAX_STAGE(x, 0x140);  // row_mirror
    DPP_MAX_STAGE(x, 0x142);  // row_bcast15
    DPP_MAX_STAGE(x, 0x143);  // row_bcast31 -> lanes 48..63 hold full max
    return x;
}

// hpg[i] = 0 bits (+0.0f) and gt-area cache for all (b,g).
__global__ void k_init(const float* __restrict__ gt, unsigned int* __restrict__ hpg,
                       float* __restrict__ gab, int BG) {
    int i = blockIdx.x * 256 + threadIdx.x;
    if (i < BG) {
        hpg[i] = 0u;
        float4 gb = ((const float4*)gt)[i];
        gab[i] = box_area(gb.x, gb.y, gb.z, gb.w);
    }
}

// Pass 1: highest_per_gt. 2 anchors/thread (512/block, 1880 blocks ->
// 7.3 waves/SIMD), g-outer, DPP wave max per g, 1 LDS atomic per g per wave,
// one coalesced 64-wide global atomic per block. Grid: (ceil(A/512), B).
__global__ __launch_bounds__(256, 8)
void pass1_hpg(const float* __restrict__ gt,
               const float* __restrict__ anchors,
               const float* __restrict__ gab,
               unsigned int* __restrict__ hpg, int A) {
    const int b = blockIdx.y;
    const int t = threadIdx.x;

    __shared__ unsigned int sred[G];
    if (t < G) sred[t] = 0u;
    __syncthreads();

    const int base = blockIdx.x * 512;
    float ax1[2], ay1[2], ax2[2], ay2[2], aar[2];
#pragma unroll
    for (int k = 0; k < 2; ++k) {
        int a = base + k * 256 + t;
        bool v = (a < A);
        float4 ab = ((const float4*)anchors)[v ? a : 0];
        ax1[k] = v ? ab.x : -3.0e38f;   // degenerate -> inter==+0, q==+0
        ay1[k] = v ? ab.y : -3.0e38f;
        ax2[k] = v ? ab.z : -3.0e38f;
        ay2[k] = v ? ab.w : -3.0e38f;
        aar[k] = box_area(ax1[k], ay1[k], ax2[k], ay2[k]);
    }

    const float4* gtb = (const float4*)gt + (size_t)b * G;
    const float* gas = gab + b * G;
    unsigned int* hb = hpg + b * G;

#pragma unroll 8
    for (int g = 0; g < G; ++g) {
        const int gv = vindex(g);              // per-lane addr -> VMEM broadcast
        const float4 gb = gtb[gv];             // global_load_dwordx4 (L1-hot)
        const float ga = gas[gv];              // global_load_dword  (L1-hot)
        float m = 0.0f;
#pragma unroll
        for (int k = 0; k < 2; ++k) {          // independent rcp/fma chains
            float inter = inter_area(gb.x, gb.y, gb.z, gb.w,
                                     ax1[k], ay1[k], ax2[k], ay2[k]);
            float denom = __fsub_rn(__fadd_rn(ga, aar[k]), inter);
            float q = div_rn(inter, denom);
            m = fmaxf(m, q);
        }
        m = wave_max_lane63(m);
        if ((t & 63) == 63)
            atomicMax(&sred[g], __float_as_uint(m));
    }
    __syncthreads();
    if (t < G) atomicMax(&hb[t], sred[t]);     // one coalesced line per block
}

// Pass 2 (R10 exact form, proven fastest): per anchor -> max/argmax over g,
// thresholds, low-quality recovery. gt/ga/hpg via uniform s_load; anchors
// per-lane. 2 anchors/thread. Grid: (ceil(A/512), B).
__global__ __launch_bounds__(256, 8)
void pass2_match(const float* __restrict__ gt,
                 const float* __restrict__ anchors,
                 const float* __restrict__ gab,
                 const unsigned int* __restrict__ hpg,
                 float* __restrict__ out_idx,
                 float* __restrict__ out_val, int A) {
    const int b = blockIdx.y;
    const int t = threadIdx.x;
    const int base = blockIdx.x * 512;

    float ax1[2], ay1[2], ax2[2], ay2[2], aar[2];
    bool val[2];
#pragma unroll
    for (int k = 0; k < 2; ++k) {
        int a = base + k * 256 + t;
        val[k] = (a < A);
        float4 ab = ((const float4*)anchors)[val[k] ? a : 0];
        ax1[k] = ab.x; ay1[k] = ab.y; ax2[k] = ab.z; ay2[k] = ab.w;
        aar[k] = box_area(ab.x, ab.y, ab.z, ab.w);
    }

    const float4* gtb = (const float4*)gt + (size_t)b * G;
    const float* gas = gab + b * G;
    const unsigned int* hpgb = hpg + b * G;

    // vmax=0/amax=0 start replicates np.argmax on an all-zero row (first idx);
    // strict > keeps the first max thereafter. q >= 0 always.
    float vmax[2] = {0.0f, 0.0f};
    int amax[2] = {0, 0};
    bool pu[2] = {false, false};
#pragma unroll 8
    for (int g = 0; g < G; ++g) {
        float4 gb = gtb[g];                        // uniform -> s_load
        float ga = gas[g];                         // uniform -> s_load
        float hg = __uint_as_float(hpgb[g]);       // uniform -> s_load
#pragma unroll
        for (int k = 0; k < 2; ++k) {
            float inter = inter_area(gb.x, gb.y, gb.z, gb.w,
                                     ax1[k], ay1[k], ax2[k], ay2[k]);
            float denom = __fsub_rn(__fadd_rn(ga, aar[k]), inter);
            float q = div_rn(inter, denom);
            pu[k] = pu[k] | (q == hg);
            if (q > vmax[k]) { vmax[k] = q; amax[k] = g; }  // first-max tie-break
        }
    }

#pragma unroll
    for (int k = 0; k < 2; ++k) {
        if (!val[k]) continue;
        int m;
        if (pu[k]) {
            m = amax[k];                    // low-quality match recovery
        } else if (vmax[k] < 0.4f) {
            m = -1;                         // BELOW_LOW_QUALITY
        } else if (vmax[k] < 0.5f) {
            m = -2;                         // BETWEEN_THRESHOLDS
        } else {
            m = amax[k];
        }
        size_t o = (size_t)b * A + (base + k * 256 + t);
        out_idx[o] = (float)m;
        out_val[o] = vmax[k];
    }
}

extern "C" void kernel_launch(void* const* d_in, const int* in_sizes, int n_in,
                              void* d_out, int out_size, void* d_ws, size_t ws_size,
                              hipStream_t stream) {
    const float* gt = (const float*)d_in[0];
    const float* anchors = (const float*)d_in[1];
    const int BG = in_sizes[0] / 4;   // B*G = 512
    const int B = BG / G;             // 8
    const int A = in_sizes[1] / 4;    // 120000

    // ws layout (u32 units): [0,512) hpg | [512,1024) ga cache
    unsigned int* hpg = (unsigned int*)d_ws;
    float* gab = (float*)d_ws + 512;

    float* out_idx = (float*)d_out;
    float* out_val = out_idx + (size_t)B * A;

    k_init<<<(BG + 255) / 256, 256, 0, stream>>>(gt, hpg, gab, BG);

    dim3 g1((A + 511) / 512, B);
    pass1_hpg<<<g1, 256, 0, stream>>>(gt, anchors, gab, hpg, A);

    dim3 g2((A + 511) / 512, B);
    pass2_match<<<g2, 256, 0, stream>>>(gt, anchors, gab, hpg, out_idx, out_val, A);
}

// Round 13
// 89.781 us; speedup vs baseline: 1.2650x; 1.2650x over previous
//
#include <hip/hip_runtime.h>

// RetinaNet matcher: gt_boxes [B=8, G=64, 4] f32, anchors [A=120000, 4] f32.
// Outputs (concat in d_out, f32): matched_idxs [B,A] (as float), matched_vals [B,A].
//
// Numerics: bit-exact vs np (absmax 0.0 R5-R12). opaque() barriers on every
// mul result -> no FMA-contraction site. div_rn() = correctly-rounded divide
// for mid-range operands (== v_div expansion with scale==1; operands provably
// mid-range). argmax tie-break = first g (strict >). IoU >= 0 -> uint
// atomicMax is bit-exact max.
//
// R13: kill the duplicated 61M IoUs. Factorization (exact):
//   q == hpg[g]  <=>  (q == m_wave[g]) && (m_wave[g] == hpg[g])
// since hpg >= m_wave >= q. Pass1 (which already computes m_wave via the DPP
// butterfly) additionally records per anchor: M (64-bit candidate mask,
// bit g = q==m_wave), vmax, amax; and per wave: mwave[64]. Pass2 becomes a
// memory-bound fixup: E bit g = (mwave[g]==hpg[g]) (wave-uniform), pu =
// (M & E) != 0, thresholds, store. Zero IoU recompute.
// Fallback: if ws_size too small for the 16.4 MB of per-anchor state, run
// the proven R10 two-pass path (template<STORE=false> + pass2_match).

static constexpr int G = 64;

__device__ __forceinline__ float opaque(float x) {
    asm volatile("" : "+v"(x));  // no-op; blocks FMA contraction across x
    return x;
}

__device__ __forceinline__ int vindex(int i) {
    asm volatile("" : "+v"(i));  // force VGPR residency; defeats scalarization
    return i;
}

__device__ __forceinline__ float box_area(float x1, float y1, float x2, float y2) {
    return opaque(__fmul_rn(__fsub_rn(x2, x1), __fsub_rn(y2, y1)));
}

__device__ __forceinline__ float inter_area(float gx1, float gy1, float gx2, float gy2,
                                            float ax1, float ay1, float ax2, float ay2) {
    float ltx = fmaxf(gx1, ax1);
    float lty = fmaxf(gy1, ay1);
    float rbx = fminf(gx2, ax2);
    float rby = fminf(gy2, ay2);
    float w = fmaxf(__fsub_rn(rbx, ltx), 0.0f);
    float h = fmaxf(__fsub_rn(rby, lty), 0.0f);
    return opaque(__fmul_rn(w, h));
}

// Correctly-rounded f32 divide for mid-range operands (no denormal/overflow).
__device__ __forceinline__ float div_rn(float n, float d) {
    float r = __builtin_amdgcn_rcpf(d);
    float e = fmaf(-d, r, 1.0f);
    r = fmaf(e, r, r);
    float q = __fmul_rn(n, r);
    float s = fmaf(-d, q, n);
    q = fmaf(s, r, q);
    s = fmaf(-d, q, n);
    q = fmaf(s, r, q);
    return q;
}

#define DPP_MAX_STAGE(x, ctrl)                                                   \
    do {                                                                         \
        int _yi = __builtin_amdgcn_update_dpp(__float_as_int(x),                 \
                                              __float_as_int(x), (ctrl),         \
                                              0xf, 0xf, false);                  \
        (x) = fmaxf((x), __int_as_float(_yi));                                   \
    } while (0)

// Full wave64 max; result valid in lane 63.
__device__ __forceinline__ float wave_max_lane63(float x) {
    DPP_MAX_STAGE(x, 0xB1);   // quad_perm xor1
    DPP_MAX_STAGE(x, 0x4E);   // quad_perm xor2
    DPP_MAX_STAGE(x, 0x141);  // row_half_mirror
    DPP_MAX_STAGE(x, 0x140);  // row_mirror
    DPP_MAX_STAGE(x, 0x142);  // row_bcast15
    DPP_MAX_STAGE(x, 0x143);  // row_bcast31
    return x;
}

// hpg[i] = 0 bits (+0.0f) and gt-area cache for all (b,g).
__global__ void k_init(const float* __restrict__ gt, unsigned int* __restrict__ hpg,
                       float* __restrict__ gab, int BG) {
    int i = blockIdx.x * 256 + threadIdx.x;
    if (i < BG) {
        hpg[i] = 0u;
        float4 gb = ((const float4*)gt)[i];
        gab[i] = box_area(gb.x, gb.y, gb.z, gb.w);
    }
}

// Pass 1: 4 anchors/thread (proven sweet spot), g-outer, DPP wave max.
// STORE: also emit per-anchor {Mlo,Mhi,vmax,amax} and per-wave mwave[64].
// Grid: (nchunks = ceil(A/1024), B), block 256.
template <bool STORE>
__global__ __launch_bounds__(256, 4)
void pass1_k(const float* __restrict__ gt,
             const float* __restrict__ anchors,
             const float* __restrict__ gab,
             unsigned int* __restrict__ hpg,
             unsigned int* __restrict__ mwave,
             unsigned int* __restrict__ Mlo,
             unsigned int* __restrict__ Mhi,
             float* __restrict__ vmaxA,
             int* __restrict__ amaxA,
             int A, int nchunks) {
    const int b = blockIdx.y;
    const int t = threadIdx.x;
    const int wv = t >> 6;

    __shared__ unsigned int sred[G];
    if (t < G) sred[t] = 0u;
    __syncthreads();

    const int base = blockIdx.x * 1024;
    float ax1[4], ay1[4], ax2[4], ay2[4], aar[4];
    bool val[4];
#pragma unroll
    for (int k = 0; k < 4; ++k) {
        int a = base + k * 256 + t;
        val[k] = (a < A);
        float4 ab = ((const float4*)anchors)[val[k] ? a : 0];
        ax1[k] = val[k] ? ab.x : -3.0e38f;   // degenerate -> inter==+0, q==+0
        ay1[k] = val[k] ? ab.y : -3.0e38f;
        ax2[k] = val[k] ? ab.z : -3.0e38f;
        ay2[k] = val[k] ? ab.w : -3.0e38f;
        aar[k] = box_area(ax1[k], ay1[k], ax2[k], ay2[k]);
    }

    const float4* gtb = (const float4*)gt + (size_t)b * G;
    const float* gas = gab + b * G;

    float vmax[4] = {0.0f, 0.0f, 0.0f, 0.0f};
    int amax[4] = {0, 0, 0, 0};
    unsigned int mlo[4] = {0u, 0u, 0u, 0u};
    unsigned int mhi[4] = {0u, 0u, 0u, 0u};

    unsigned int* mwv = nullptr;
    if constexpr (STORE) {
        const int wgid = (b * nchunks + blockIdx.x) * 4 + wv;
        mwv = mwave + (size_t)wgid * 64;
    }

    // two half-loops so the candidate-bit shift targets a fixed 32-bit half
#pragma unroll 1
    for (int half = 0; half < 2; ++half) {
#pragma unroll 8
        for (int gg = 0; gg < 32; ++gg) {
            const int g = half * 32 + gg;
            const int gv = vindex(g);              // VMEM broadcast (L1-hot)
            const float4 gb = gtb[gv];
            const float ga = gas[gv];
            float q[4];
            float m = 0.0f;
#pragma unroll
            for (int k = 0; k < 4; ++k) {
                float inter = inter_area(gb.x, gb.y, gb.z, gb.w,
                                         ax1[k], ay1[k], ax2[k], ay2[k]);
                float denom = __fsub_rn(__fadd_rn(ga, aar[k]), inter);
                q[k] = div_rn(inter, denom);
                m = fmaxf(m, q[k]);
            }
            m = wave_max_lane63(m);
            if constexpr (STORE) {
                float ms = __int_as_float(
                    __builtin_amdgcn_readlane(__float_as_int(m), 63));
#pragma unroll
                for (int k = 0; k < 4; ++k) {
                    unsigned int cb = (q[k] == ms) ? 1u : 0u;
                    if (half == 0) mlo[k] |= cb << gg;
                    else           mhi[k] |= cb << gg;
                    if (q[k] > vmax[k]) { vmax[k] = q[k]; amax[k] = g; }
                }
                if ((t & 63) == 63) {
                    atomicMax(&sred[g], __float_as_uint(m));
                    mwv[g] = __float_as_uint(m);
                }
            } else {
                if ((t & 63) == 63)
                    atomicMax(&sred[g], __float_as_uint(m));
            }
        }
    }

    if constexpr (STORE) {
#pragma unroll
        for (int k = 0; k < 4; ++k) {
            if (!val[k]) continue;
            size_t idx = (size_t)b * A + (base + k * 256 + t);
            Mlo[idx] = mlo[k];
            Mhi[idx] = mhi[k];
            vmaxA[idx] = vmax[k];
            amaxA[idx] = amax[k];
        }
    }

    __syncthreads();
    if (t < G) atomicMax(&hpg[b * G + t], sred[t]);
}

// Pass 2 (fused path): pure fixup, no IoU. E bit g = (mwave[g]==hpg[g])
// (wave-uniform SALU); pu = (M & E) != 0; thresholds; store.
// SAME grid/partition as pass1 so wave -> mwave mapping is identical.
__global__ __launch_bounds__(256, 8)
void pass2_lite(const unsigned int* __restrict__ hpg,
                const unsigned int* __restrict__ mwave,
                const unsigned int* __restrict__ Mlo,
                const unsigned int* __restrict__ Mhi,
                const float* __restrict__ vmaxA,
                const int* __restrict__ amaxA,
                float* __restrict__ out_idx,
                float* __restrict__ out_val,
                int A, int nchunks) {
    const int b = blockIdx.y;
    const int t = threadIdx.x;
    const int wv = t >> 6;
    const int wgid = (b * nchunks + blockIdx.x) * 4 + wv;

    const unsigned int* mwv = mwave + (size_t)wgid * 64;
    const unsigned int* hb = hpg + b * G;

    unsigned int Elo = 0u, Ehi = 0u;
#pragma unroll 8
    for (int g = 0; g < 32; ++g)
        Elo |= (mwv[g] == hb[g]) ? (1u << g) : 0u;        // uniform -> SALU
#pragma unroll 8
    for (int g = 0; g < 32; ++g)
        Ehi |= (mwv[32 + g] == hb[32 + g]) ? (1u << g) : 0u;

    const int base = blockIdx.x * 1024;
#pragma unroll
    for (int k = 0; k < 4; ++k) {
        int a = base + k * 256 + t;
        if (a >= A) continue;
        size_t idx = (size_t)b * A + a;
        unsigned int ml = Mlo[idx];
        unsigned int mh = Mhi[idx];
        float vm = vmaxA[idx];
        int am = amaxA[idx];
        bool pu = ((ml & Elo) | (mh & Ehi)) != 0u;
        int m;
        if (pu) {
            m = am;                          // low-quality match recovery
        } else if (vm < 0.4f) {
            m = -1;                          // BELOW_LOW_QUALITY
        } else if (vm < 0.5f) {
            m = -2;                          // BETWEEN_THRESHOLDS
        } else {
            m = am;
        }
        out_idx[idx] = (float)m;
        out_val[idx] = vm;
    }
}

// Fallback pass 2 (R10 exact form): full recompute. Used when ws too small.
__global__ __launch_bounds__(256, 8)
void pass2_match(const float* __restrict__ gt,
                 const float* __restrict__ anchors,
                 const float* __restrict__ gab,
                 const unsigned int* __restrict__ hpg,
                 float* __restrict__ out_idx,
                 float* __restrict__ out_val, int A) {
    const int b = blockIdx.y;
    const int t = threadIdx.x;
    const int base = blockIdx.x * 512;

    float ax1[2], ay1[2], ax2[2], ay2[2], aar[2];
    bool val[2];
#pragma unroll
    for (int k = 0; k < 2; ++k) {
        int a = base + k * 256 + t;
        val[k] = (a < A);
        float4 ab = ((const float4*)anchors)[val[k] ? a : 0];
        ax1[k] = ab.x; ay1[k] = ab.y; ax2[k] = ab.z; ay2[k] = ab.w;
        aar[k] = box_area(ab.x, ab.y, ab.z, ab.w);
    }

    const float4* gtb = (const float4*)gt + (size_t)b * G;
    const float* gas = gab + b * G;
    const unsigned int* hpgb = hpg + b * G;

    float vmax[2] = {0.0f, 0.0f};
    int amax[2] = {0, 0};
    bool pu[2] = {false, false};
#pragma unroll 8
    for (int g = 0; g < G; ++g) {
        float4 gb = gtb[g];
        float ga = gas[g];
        float hg = __uint_as_float(hpgb[g]);
#pragma unroll
        for (int k = 0; k < 2; ++k) {
            float inter = inter_area(gb.x, gb.y, gb.z, gb.w,
                                     ax1[k], ay1[k], ax2[k], ay2[k]);
            float denom = __fsub_rn(__fadd_rn(ga, aar[k]), inter);
            float q = div_rn(inter, denom);
            pu[k] = pu[k] | (q == hg);
            if (q > vmax[k]) { vmax[k] = q; amax[k] = g; }
        }
    }

#pragma unroll
    for (int k = 0; k < 2; ++k) {
        if (!val[k]) continue;
        int m;
        if (pu[k]) m = amax[k];
        else if (vmax[k] < 0.4f) m = -1;
        else if (vmax[k] < 0.5f) m = -2;
        else m = amax[k];
        size_t o = (size_t)b * A + (base + k * 256 + t);
        out_idx[o] = (float)m;
        out_val[o] = vmax[k];
    }
}

extern "C" void kernel_launch(void* const* d_in, const int* in_sizes, int n_in,
                              void* d_out, int out_size, void* d_ws, size_t ws_size,
                              hipStream_t stream) {
    const float* gt = (const float*)d_in[0];
    const float* anchors = (const float*)d_in[1];
    const int BG = in_sizes[0] / 4;   // B*G = 512
    const int B = BG / G;             // 8
    const int A = in_sizes[1] / 4;    // 120000

    const int nchunks = (A + 1023) / 1024;
    const int nwaves = nchunks * B * 4;

    // ws layout (u32 units):
    // [0,512) hpg | [512,1024) ga | [1024, +nwaves*64) mwave |
    // then Mlo[B*A], Mhi[B*A], vmax[B*A], amax[B*A]
    unsigned int* ws = (unsigned int*)d_ws;
    unsigned int* hpg = ws;
    float* gab = (float*)(ws + 512);
    unsigned int* mwave = ws + 1024;
    size_t mlo_off = 1024 + (size_t)nwaves * 64;
    unsigned int* Mlo = ws + mlo_off;
    unsigned int* Mhi = Mlo + (size_t)B * A;
    float* vmaxA = (float*)(Mhi + (size_t)B * A);
    int* amaxA = (int*)(vmaxA + (size_t)B * A);
    const size_t need = (mlo_off + 4 * (size_t)B * A) * 4;
    const bool fused = (ws_size >= need);

    float* out_idx = (float*)d_out;
    float* out_val = out_idx + (size_t)B * A;

    k_init<<<(BG + 255) / 256, 256, 0, stream>>>(gt, hpg, gab, BG);

    dim3 g1(nchunks, B);
    if (fused) {
        pass1_k<true><<<g1, 256, 0, stream>>>(gt, anchors, gab, hpg, mwave,
                                              Mlo, Mhi, vmaxA, amaxA, A, nchunks);
        pass2_lite<<<g1, 256, 0, stream>>>(hpg, mwave, Mlo, Mhi, vmaxA, amaxA,
                                           out_idx, out_val, A, nchunks);
    } else {
        pass1_k<false><<<g1, 256, 0, stream>>>(gt, anchors, gab, hpg, mwave,
                                               Mlo, Mhi, vmaxA, amaxA, A, nchunks);
        dim3 g2((A + 511) / 512, B);
        pass2_match<<<g2, 256, 0, stream>>>(gt, anchors, gab, hpg,
                                            out_idx, out_val, A);
    }
}

// Round 14
// 76.113 us; speedup vs baseline: 1.4921x; 1.1796x over previous
//
#include <hip/hip_runtime.h>

// RetinaNet matcher: gt_boxes [B=8, G=64, 4] f32, anchors [A=120000, 4] f32.
// Outputs (concat in d_out, f32): matched_idxs [B,A] (as float), matched_vals [B,A].
//
// Numerics: bit-exact vs np (absmax 0.0 R5-R13). opaque() barriers on every
// mul result -> no FMA-contraction site. div_rn() = correctly-rounded divide
// for mid-range operands (== v_div expansion with scale==1). argmax
// tie-break = first g (strict >). IoU >= 0 -> uint atomicMax bit-exact.
//
// R14: coarsen R13's factorization from wave to block granularity:
//   q == hpg[g]  <=>  (q == m_block[g]) && (m_block[g] == hpg[g])
// (chain q <= m_block <= hpg). Pass1 already has m_block[g] in LDS (sred);
// drop ALL per-anchor mask bookkeeping (readlane + cmp/or per k per g +
// 8 MB Mlo/Mhi stores) and dump sred[64] per block (242 KB). Pass2 builds
// E[g] = (sred_blk[g]==hpg[g]) - expected ~0.07 set bits per block - and
// ONLY for set bits recomputes q (identical bit-exact pipeline) to OR into
// pu; otherwise it is a pure memory-bound threshold pass on vmax/amax.
// Fallback (ws too small): proven R10 two-pass recompute path.

static constexpr int G = 64;

__device__ __forceinline__ float opaque(float x) {
    asm volatile("" : "+v"(x));  // no-op; blocks FMA contraction across x
    return x;
}

__device__ __forceinline__ int vindex(int i) {
    asm volatile("" : "+v"(i));  // force VGPR residency; defeats scalarization
    return i;
}

__device__ __forceinline__ float box_area(float x1, float y1, float x2, float y2) {
    return opaque(__fmul_rn(__fsub_rn(x2, x1), __fsub_rn(y2, y1)));
}

__device__ __forceinline__ float inter_area(float gx1, float gy1, float gx2, float gy2,
                                            float ax1, float ay1, float ax2, float ay2) {
    float ltx = fmaxf(gx1, ax1);
    float lty = fmaxf(gy1, ay1);
    float rbx = fminf(gx2, ax2);
    float rby = fminf(gy2, ay2);
    float w = fmaxf(__fsub_rn(rbx, ltx), 0.0f);
    float h = fmaxf(__fsub_rn(rby, lty), 0.0f);
    return opaque(__fmul_rn(w, h));
}

// Correctly-rounded f32 divide for mid-range operands (no denormal/overflow).
__device__ __forceinline__ float div_rn(float n, float d) {
    float r = __builtin_amdgcn_rcpf(d);
    float e = fmaf(-d, r, 1.0f);
    r = fmaf(e, r, r);
    float q = __fmul_rn(n, r);
    float s = fmaf(-d, q, n);
    q = fmaf(s, r, q);
    s = fmaf(-d, q, n);
    q = fmaf(s, r, q);
    return q;
}

#define DPP_MAX_STAGE(x, ctrl)                                                   \
    do {                                                                         \
        int _yi = __builtin_amdgcn_update_dpp(__float_as_int(x),                 \
                                              __float_as_int(x), (ctrl),         \
                                              0xf, 0xf, false);                  \
        (x) = fmaxf((x), __int_as_float(_yi));                                   \
    } while (0)

// Full wave64 max; result valid in lane 63.
__device__ __forceinline__ float wave_max_lane63(float x) {
    DPP_MAX_STAGE(x, 0xB1);   // quad_perm xor1
    DPP_MAX_STAGE(x, 0x4E);   // quad_perm xor2
    DPP_MAX_STAGE(x, 0x141);  // row_half_mirror
    DPP_MAX_STAGE(x, 0x140);  // row_mirror
    DPP_MAX_STAGE(x, 0x142);  // row_bcast15
    DPP_MAX_STAGE(x, 0x143);  // row_bcast31
    return x;
}

// hpg[i] = 0 bits (+0.0f) and gt-area cache for all (b,g).
__global__ void k_init(const float* __restrict__ gt, unsigned int* __restrict__ hpg,
                       float* __restrict__ gab, int BG) {
    int i = blockIdx.x * 256 + threadIdx.x;
    if (i < BG) {
        hpg[i] = 0u;
        float4 gb = ((const float4*)gt)[i];
        gab[i] = box_area(gb.x, gb.y, gb.z, gb.w);
    }
}

// Pass 1: 4 anchors/thread, g-outer, DPP wave max, LDS block max.
// STORE: track per-anchor vmax/amax, dump sred[64] per block + vmax/amax.
// Grid: (nchunks = ceil(A/1024), B), block 256.
template <bool STORE>
__global__ __launch_bounds__(256, 4)
void pass1_k(const float* __restrict__ gt,
             const float* __restrict__ anchors,
             const float* __restrict__ gab,
             unsigned int* __restrict__ hpg,
             unsigned int* __restrict__ sredg,
             float* __restrict__ vmaxA,
             int* __restrict__ amaxA,
             int A, int nchunks) {
    const int b = blockIdx.y;
    const int t = threadIdx.x;

    __shared__ unsigned int sred[G];
    if (t < G) sred[t] = 0u;
    __syncthreads();

    const int base = blockIdx.x * 1024;
    float ax1[4], ay1[4], ax2[4], ay2[4], aar[4];
    bool val[4];
#pragma unroll
    for (int k = 0; k < 4; ++k) {
        int a = base + k * 256 + t;
        val[k] = (a < A);
        float4 ab = ((const float4*)anchors)[val[k] ? a : 0];
        ax1[k] = val[k] ? ab.x : -3.0e38f;   // degenerate -> inter==+0, q==+0
        ay1[k] = val[k] ? ab.y : -3.0e38f;
        ax2[k] = val[k] ? ab.z : -3.0e38f;
        ay2[k] = val[k] ? ab.w : -3.0e38f;
        aar[k] = box_area(ax1[k], ay1[k], ax2[k], ay2[k]);
    }

    const float4* gtb = (const float4*)gt + (size_t)b * G;
    const float* gas = gab + b * G;

    float vmax[4] = {0.0f, 0.0f, 0.0f, 0.0f};
    int amax[4] = {0, 0, 0, 0};

#pragma unroll 8
    for (int g = 0; g < G; ++g) {
        const int gv = vindex(g);              // VMEM broadcast (L1-hot)
        const float4 gb = gtb[gv];
        const float ga = gas[gv];
        float m = 0.0f;
#pragma unroll
        for (int k = 0; k < 4; ++k) {
            float inter = inter_area(gb.x, gb.y, gb.z, gb.w,
                                     ax1[k], ay1[k], ax2[k], ay2[k]);
            float denom = __fsub_rn(__fadd_rn(ga, aar[k]), inter);
            float q = div_rn(inter, denom);
            if constexpr (STORE) {
                if (q > vmax[k]) { vmax[k] = q; amax[k] = g; }  // first-max
            }
            m = fmaxf(m, q);
        }
        m = wave_max_lane63(m);
        if ((t & 63) == 63)
            atomicMax(&sred[g], __float_as_uint(m));
    }

    if constexpr (STORE) {
#pragma unroll
        for (int k = 0; k < 4; ++k) {
            if (!val[k]) continue;
            size_t idx = (size_t)b * A + (base + k * 256 + t);
            vmaxA[idx] = vmax[k];
            amaxA[idx] = amax[k];
        }
    }

    __syncthreads();
    if (t < G) {
        atomicMax(&hpg[b * G + t], sred[t]);
        if constexpr (STORE)
            sredg[(size_t)(b * nchunks + blockIdx.x) * G + t] = sred[t];
    }
}

// Pass 2 (fused): E[g] = (sred_blk[g]==hpg[g]) via SALU; for the rare set
// bits, recompute q bit-exactly and OR pu; else pure threshold pass.
// SAME chunk mapping as pass1. Grid: (nchunks, B), block 256.
__global__ __launch_bounds__(256, 8)
void pass2_lite(const float* __restrict__ gt,
                const float* __restrict__ anchors,
                const float* __restrict__ gab,
                const unsigned int* __restrict__ hpg,
                const unsigned int* __restrict__ sredg,
                const float* __restrict__ vmaxA,
                const int* __restrict__ amaxA,
                float* __restrict__ out_idx,
                float* __restrict__ out_val,
                int A, int nchunks) {
    const int b = blockIdx.y;
    const int t = threadIdx.x;
    const int base = blockIdx.x * 1024;

    const unsigned int* sb = sredg + (size_t)(b * nchunks + blockIdx.x) * G;
    const unsigned int* hb = hpg + b * G;

    // E: block-uniform (SALU) 64-bit mask of g's whose block max == global max
    unsigned long long E = 0ull;
#pragma unroll 16
    for (int g = 0; g < G; ++g)
        E |= (sb[g] == hb[g]) ? (1ull << g) : 0ull;

    bool pu[4] = {false, false, false, false};

    if (E != 0ull) {                    // rare; block-uniform branch
        const float4* gtb = (const float4*)gt + (size_t)b * G;
        const float* gas = gab + b * G;
        float ax1[4], ay1[4], ax2[4], ay2[4], aar[4];
#pragma unroll
        for (int k = 0; k < 4; ++k) {
            int a = base + k * 256 + t;
            bool v = (a < A);
            float4 ab = ((const float4*)anchors)[v ? a : 0];
            ax1[k] = v ? ab.x : -3.0e38f;
            ay1[k] = v ? ab.y : -3.0e38f;
            ax2[k] = v ? ab.z : -3.0e38f;
            ay2[k] = v ? ab.w : -3.0e38f;
            aar[k] = box_area(ax1[k], ay1[k], ax2[k], ay2[k]);
        }
        unsigned long long e = E;
        while (e) {
            int g = __builtin_ctzll(e);
            e &= e - 1;
            float4 gb = gtb[g];
            float ga = gas[g];
            float hgf = __uint_as_float(hb[g]);
#pragma unroll
            for (int k = 0; k < 4; ++k) {
                float inter = inter_area(gb.x, gb.y, gb.z, gb.w,
                                         ax1[k], ay1[k], ax2[k], ay2[k]);
                float denom = __fsub_rn(__fadd_rn(ga, aar[k]), inter);
                float q = div_rn(inter, denom);
                pu[k] = pu[k] | (q == hgf);
            }
        }
    }

#pragma unroll
    for (int k = 0; k < 4; ++k) {
        int a = base + k * 256 + t;
        if (a >= A) continue;
        size_t idx = (size_t)b * A + a;
        float vm = vmaxA[idx];
        int am = amaxA[idx];
        int m;
        if (pu[k]) {
            m = am;                          // low-quality match recovery
        } else if (vm < 0.4f) {
            m = -1;                          // BELOW_LOW_QUALITY
        } else if (vm < 0.5f) {
            m = -2;                          // BETWEEN_THRESHOLDS
        } else {
            m = am;
        }
        out_idx[idx] = (float)m;
        out_val[idx] = vm;
    }
}

// Fallback pass 2 (R10 exact form): full recompute. Used when ws too small.
__global__ __launch_bounds__(256, 8)
void pass2_match(const float* __restrict__ gt,
                 const float* __restrict__ anchors,
                 const float* __restrict__ gab,
                 const unsigned int* __restrict__ hpg,
                 float* __restrict__ out_idx,
                 float* __restrict__ out_val, int A) {
    const int b = blockIdx.y;
    const int t = threadIdx.x;
    const int base = blockIdx.x * 512;

    float ax1[2], ay1[2], ax2[2], ay2[2], aar[2];
    bool val[2];
#pragma unroll
    for (int k = 0; k < 2; ++k) {
        int a = base + k * 256 + t;
        val[k] = (a < A);
        float4 ab = ((const float4*)anchors)[val[k] ? a : 0];
        ax1[k] = ab.x; ay1[k] = ab.y; ax2[k] = ab.z; ay2[k] = ab.w;
        aar[k] = box_area(ab.x, ab.y, ab.z, ab.w);
    }

    const float4* gtb = (const float4*)gt + (size_t)b * G;
    const float* gas = gab + b * G;
    const unsigned int* hpgb = hpg + b * G;

    float vmax[2] = {0.0f, 0.0f};
    int amax[2] = {0, 0};
    bool pu[2] = {false, false};
#pragma unroll 8
    for (int g = 0; g < G; ++g) {
        float4 gb = gtb[g];
        float ga = gas[g];
        float hg = __uint_as_float(hpgb[g]);
#pragma unroll
        for (int k = 0; k < 2; ++k) {
            float inter = inter_area(gb.x, gb.y, gb.z, gb.w,
                                     ax1[k], ay1[k], ax2[k], ay2[k]);
            float denom = __fsub_rn(__fadd_rn(ga, aar[k]), inter);
            float q = div_rn(inter, denom);
            pu[k] = pu[k] | (q == hg);
            if (q > vmax[k]) { vmax[k] = q; amax[k] = g; }
        }
    }

#pragma unroll
    for (int k = 0; k < 2; ++k) {
        if (!val[k]) continue;
        int m;
        if (pu[k]) m = amax[k];
        else if (vmax[k] < 0.4f) m = -1;
        else if (vmax[k] < 0.5f) m = -2;
        else m = amax[k];
        size_t o = (size_t)b * A + (base + k * 256 + t);
        out_idx[o] = (float)m;
        out_val[o] = vmax[k];
    }
}

extern "C" void kernel_launch(void* const* d_in, const int* in_sizes, int n_in,
                              void* d_out, int out_size, void* d_ws, size_t ws_size,
                              hipStream_t stream) {
    const float* gt = (const float*)d_in[0];
    const float* anchors = (const float*)d_in[1];
    const int BG = in_sizes[0] / 4;   // B*G = 512
    const int B = BG / G;             // 8
    const int A = in_sizes[1] / 4;    // 120000

    const int nchunks = (A + 1023) / 1024;

    // ws layout (u32 units):
    // [0,512) hpg | [512,1024) ga | [1024, +nchunks*B*64) sredg |
    // then vmaxA[B*A] f32 | amaxA[B*A] i32
    unsigned int* ws = (unsigned int*)d_ws;
    unsigned int* hpg = ws;
    float* gab = (float*)(ws + 512);
    unsigned int* sredg = ws + 1024;
    size_t voff = 1024 + (size_t)nchunks * B * G;
    float* vmaxA = (float*)(ws + voff);
    int* amaxA = (int*)(vmaxA + (size_t)B * A);
    const size_t need = (voff + 2 * (size_t)B * A) * 4;
    const bool fused = (ws_size >= need);

    float* out_idx = (float*)d_out;
    float* out_val = out_idx + (size_t)B * A;

    k_init<<<(BG + 255) / 256, 256, 0, stream>>>(gt, hpg, gab, BG);

    dim3 g1(nchunks, B);
    if (fused) {
        pass1_k<true><<<g1, 256, 0, stream>>>(gt, anchors, gab, hpg, sredg,
                                              vmaxA, amaxA, A, nchunks);
        pass2_lite<<<g1, 256, 0, stream>>>(gt, anchors, gab, hpg, sredg,
                                           vmaxA, amaxA, out_idx, out_val,
                                           A, nchunks);
    } else {
        pass1_k<false><<<g1, 256, 0, stream>>>(gt, anchors, gab, hpg, sredg,
                                               vmaxA, amaxA, A, nchunks);
        dim3 g2((A + 511) / 512, B);
        pass2_match<<<g2, 256, 0, stream>>>(gt, anchors, gab, hpg,
                                            out_idx, out_val, A);
    }
}